// Round 7
// baseline (3349.420 us; speedup 1.0000x reference)
//
#include <hip/hip_runtime.h>

#define DD 1536
#define TT 512
#define BB 64
#define BD (BB*DD)      /* 98304 */
#define TBD (TT*BD)     /* 50331648 */
#define NWG 96          /* 24 feature-groups x 4 batch-quadrants */

typedef __attribute__((ext_vector_type(8))) short short8;
typedef __attribute__((ext_vector_type(4))) float f32x4;
typedef __attribute__((ext_vector_type(4))) unsigned uint4v;
typedef unsigned long long u64;

__device__ __forceinline__ short f2bf(float f) {
  unsigned u = __builtin_bit_cast(unsigned, f);
  u += 0x7FFFu + ((u >> 16) & 1u);   // RNE
  return (short)(u >> 16);
}

// coherent (device-scope, L1/L2-bypassing) 8B store -> Infinity Cache, fire-and-forget
__device__ __forceinline__ void st_coh_b64(u64* p, u64 v) {
  asm volatile("global_store_dwordx2 %0, %1, off sc0 sc1" :: "v"(p), "v"(v) : "memory");
}

// coherent 16B load from Infinity Cache (bypasses L1/L2)
#define LDQ(dst, addr, imm) \
  asm volatile("global_load_dwordx4 %0, %1, off offset:" #imm " sc0 sc1" \
               : "=v"(dst) : "v"(addr) : "memory")

// all 8 tagged words carry `tag` in their low 8 bits?
__device__ __forceinline__ bool tagok(uint4v a, uint4v b, unsigned tag) {
  unsigned m = ((a[0]^tag) | (a[1]^tag) | (a[2]^tag) | (a[3]^tag)
              | (b[0]^tag) | (b[1]^tag) | (b[2]^tag) | (b[3]^tag)) & 255u;
  return m == 0u;
}

// 8 tagged words -> 8 bf16 (top halves), MFMA A-frag order (consecutive K)
__device__ __forceinline__ short8 rp(uint4v a, uint4v b) {
  uint4v d;
  d[0] = (a[0] >> 16) | (a[1] & 0xFFFF0000u);
  d[1] = (a[2] >> 16) | (a[3] & 0xFFFF0000u);
  d[2] = (b[0] >> 16) | (b[1] & 0xFFFF0000u);
  d[3] = (b[2] >> 16) | (b[3] & 0xFFFF0000u);
  return __builtin_bit_cast(short8, d);
}

// ---------------- power iteration helpers (f32 exact) ----------------

__global__ __launch_bounds__(256) void k_matvec_row(
    const float* __restrict__ W, const float* __restrict__ x, float* __restrict__ y) {
  int wave = (blockIdx.x * 256 + threadIdx.x) >> 6;
  int lane = threadIdx.x & 63;
  const float* Wr = W + (size_t)wave * DD;
  float acc = 0.f;
  for (int j = lane; j < DD; j += 64) acc += Wr[j] * x[j];
  for (int off = 32; off; off >>= 1) acc += __shfl_down(acc, off, 64);
  if (lane == 0) y[wave] = acc;
}

__global__ __launch_bounds__(256) void k_matvec_col(
    const float* __restrict__ W, const float* __restrict__ x, float* __restrict__ y) {
  int j = blockIdx.x * 256 + threadIdx.x;
  int i0 = blockIdx.y * 192;
  float acc = 0.f;
  for (int i = i0; i < i0 + 192; ++i) acc += W[(size_t)i * DD + j] * x[i];
  atomicAdd(&y[j], acc);
}

__global__ __launch_bounds__(256) void k_scale(
    const float* __restrict__ t5, const float* __restrict__ t6,
    const float* __restrict__ log_radius, float* __restrict__ s_out) {
  __shared__ float red[8];
  int tid = threadIdx.x;
  float a5 = 0.f, a6 = 0.f;
  for (int i = tid; i < DD; i += 256) { float v5 = t5[i], v6 = t6[i]; a5 += v5*v5; a6 += v6*v6; }
  for (int off = 32; off; off >>= 1) { a5 += __shfl_down(a5, off, 64); a6 += __shfl_down(a6, off, 64); }
  int w = tid >> 6, lane = tid & 63;
  if (lane == 0) { red[w] = a5; red[4 + w] = a6; }
  __syncthreads();
  if (tid == 0) {
    float s5 = red[0] + red[1] + red[2] + red[3];
    float s6 = red[4] + red[5] + red[6] + red[7];
    float sigma = sqrtf(s6 / s5);
    float lr = log_radius[0];
    float target = 0.999f / (1.f + expf(-lr));
    s_out[0] = target / (sigma + 1e-8f);
  }
}

// ---------------- phase 1: A = x @ Wx^T + b -> d_out[outs region] ----------------
__global__ __launch_bounds__(256) void k_gemm_xA(
    const float* __restrict__ x, const float* __restrict__ Wx,
    const float* __restrict__ bias, float* __restrict__ Aout) {
  __shared__ short As[128 * 64];
  __shared__ short Bs[128 * 64];
  const int tid = threadIdx.x;
  const int lane = tid & 63;
  const int w = tid >> 6;
  const int n0 = blockIdx.x * 128;
  const int m0 = blockIdx.y * 128;
  const int mq = (w >> 1) * 64;
  const int nq = (w & 1) * 64;

  f32x4 acc[4][4];
#pragma unroll
  for (int i = 0; i < 4; ++i)
#pragma unroll
    for (int j = 0; j < 4; ++j) acc[i][j] = (f32x4){0.f, 0.f, 0.f, 0.f};

  const int r0 = tid >> 3;
  const int c8 = tid & 7;

  for (int k0 = 0; k0 < DD; k0 += 64) {
    __syncthreads();
#pragma unroll
    for (int c = 0; c < 4; ++c) {
      int row = c * 32 + r0;
      const float4* gx = (const float4*)(x + (size_t)(m0 + row) * DD + k0 + c8 * 8);
      const float4* gw = (const float4*)(Wx + (size_t)(n0 + row) * DD + k0 + c8 * 8);
      float4 x0 = gx[0], x1 = gx[1];
      float4 w0 = gw[0], w1 = gw[1];
      short8 xv, wv;
      xv[0]=f2bf(x0.x); xv[1]=f2bf(x0.y); xv[2]=f2bf(x0.z); xv[3]=f2bf(x0.w);
      xv[4]=f2bf(x1.x); xv[5]=f2bf(x1.y); xv[6]=f2bf(x1.z); xv[7]=f2bf(x1.w);
      wv[0]=f2bf(w0.x); wv[1]=f2bf(w0.y); wv[2]=f2bf(w0.z); wv[3]=f2bf(w0.w);
      wv[4]=f2bf(w1.x); wv[5]=f2bf(w1.y); wv[6]=f2bf(w1.z); wv[7]=f2bf(w1.w);
      int so = (row * 64 + c8 * 8) ^ ((row & 7) << 3);
      *(short8*)&As[so] = xv;
      *(short8*)&Bs[so] = wv;
    }
    __syncthreads();
#pragma unroll
    for (int kk = 0; kk < 64; kk += 32) {
      short8 af[4], bfr[4];
#pragma unroll
      for (int f = 0; f < 4; ++f) {
        int ar = mq + f * 16 + (lane & 15);
        int k = kk + ((lane >> 4) << 3);
        af[f] = *(const short8*)&As[(ar * 64 + k) ^ ((ar & 7) << 3)];
        int br = nq + f * 16 + (lane & 15);
        bfr[f] = *(const short8*)&Bs[(br * 64 + k) ^ ((br & 7) << 3)];
      }
#pragma unroll
      for (int i = 0; i < 4; ++i)
#pragma unroll
        for (int j = 0; j < 4; ++j)
          acc[i][j] = __builtin_amdgcn_mfma_f32_16x16x32_bf16(af[i], bfr[j], acc[i][j], 0, 0, 0);
    }
  }
#pragma unroll
  for (int i = 0; i < 4; ++i) {
    int rbase = m0 + mq + i * 16 + ((lane >> 4) << 2);
#pragma unroll
    for (int j = 0; j < 4; ++j) {
      int col = n0 + nq + j * 16 + (lane & 15);
      float bv = bias[col];
#pragma unroll
      for (int r = 0; r < 4; ++r)
        Aout[(size_t)(rbase + r) * DD + col] = acc[i][j][r] + bv;
    }
  }
}

// ---------------- phase 2: recurrence, tag-validated fence-free exchange ----------------
// h exchanged as 32-bit words: bf16(h)<<16 | (step&255). Producers fire coherent
// stores and proceed (no ack, no flag, no fence). Consumers poll the data itself,
// retrying only stale groups (wave-uniform). 2-buffer ping-pong proven safe by
// induction: writer of h[t+2] must first validate all of h[t+1], which requires
// every WG's reads of h[t] to have completed.
__global__ __launch_bounds__(512, 2) void k_recur(
    const float* __restrict__ Wh, const float* __restrict__ h0,
    const float* __restrict__ z, const float* __restrict__ sp,
    float* __restrict__ outs, float* __restrict__ hall,
    float* __restrict__ hb0, float* __restrict__ hb1) {
  __shared__ f32x4 REDS[2][2048];  // double-buffered: 2 x 32 KB
  const int tid = threadIdx.x;
  const int lane = tid & 63;
  const int wv = tid >> 6;         // 0..7
  const int wgid = blockIdx.x;     // 0..95
  const int fg = wgid >> 2;        // 0..23
  const int mq = wgid & 3;
  const int n0 = fg * 64;
  const int m0 = mq * 16;

  const int nl = lane & 15;
  const int hi8 = (lane >> 4) << 3;
  const int kw = wv * 192;         // wave's K-slice base

  // ---- one-time: Wh tile -> registers (f32 -> bf16) ----
  short8 bfr[6][4];
#pragma unroll
  for (int j = 0; j < 6; ++j)
#pragma unroll
    for (int f = 0; f < 4; ++f) {
      const float* gp = Wh + (size_t)(n0 + f * 16 + nl) * DD + kw + j * 32 + hi8;
      float4 a0 = *(const float4*)gp;
      float4 a1 = *(const float4*)(gp + 4);
      short8 v;
      v[0]=f2bf(a0.x); v[1]=f2bf(a0.y); v[2]=f2bf(a0.z); v[3]=f2bf(a0.w);
      v[4]=f2bf(a1.x); v[5]=f2bf(a1.y); v[6]=f2bf(a1.z); v[7]=f2bf(a1.w);
      bfr[j][f] = v;
    }

  // epilogue geometry: 2 consecutive outputs per thread
  const int o = tid * 2;
  const int r = o >> 6;            // 0..15
  const int c = o & 63;            // even
  const int f0 = c >> 4;
  const int c15 = c & 15;
  const int l2a = ((r >> 2) << 4) | c15;
  const int l2b = l2a + 1;
  const int ri = r & 3;
  const size_t eidx = (size_t)(m0 + r) * DD + n0 + c;       // element in [B,D]
  const size_t aoff = (size_t)(m0 + nl) * DD + kw + hi8;    // A-load base, floats

  // init own tile: hall[0] = h0 (f32), hb0 = tagged(bf16(h0), tag 0)
  {
    float vx = h0[eidx], vy = h0[eidx + 1];
    hall[eidx] = vx; hall[eidx + 1] = vy;
    unsigned w0 = ((unsigned)(unsigned short)f2bf(vx) << 16) | 0u;
    unsigned w1 = ((unsigned)(unsigned short)f2bf(vy) << 16) | 0u;
    st_coh_b64((u64*)(hb0 + eidx), (u64)w0 | ((u64)w1 << 32));
  }
  const float sv = sp[0];

  // prefetch A, z for t = 0 (plain cached)
  float pa = outs[eidx], pay = outs[eidx + 1];
  float pz = z[eidx], pzy = z[eidx + 1];

  for (int t = 0; t < TT; ++t) {
    const float* Hg = (t & 1) ? hb1 : hb0;
    float* Hn = (t & 1) ? hb0 : hb1;
    const float* hp = Hg + aoff;
    const unsigned tag = (unsigned)(t & 255);
    const bool last = (t == TT - 1);

    // early prefetch of next-step A,z (drained by the poll's vmcnt but issued first)
    float pan = 0.f, payn = 0.f, pzn = 0.f, pzyn = 0.f;
    size_t nb = (size_t)t * BD + BD + eidx;
    if (!last) { pan = outs[nb]; payn = outs[nb + 1]; pzn = z[nb]; pzyn = z[nb + 1]; }

    // ---- tag-validated poll of h[t] (12 coherent 16B loads, group retry) ----
    uint4v qa0, qb0, qa1, qb1, qa2, qb2, qa3, qb3, qa4, qb4, qa5, qb5;
    bool v0 = false, v1 = false, v2 = false, v3 = false, v4 = false, v5 = false;
    for (;;) {
      if (!__all(v0)) { LDQ(qa0, hp, 0);   LDQ(qb0, hp, 16);  }
      if (!__all(v1)) { LDQ(qa1, hp, 128); LDQ(qb1, hp, 144); }
      if (!__all(v2)) { LDQ(qa2, hp, 256); LDQ(qb2, hp, 272); }
      if (!__all(v3)) { LDQ(qa3, hp, 384); LDQ(qb3, hp, 400); }
      if (!__all(v4)) { LDQ(qa4, hp, 512); LDQ(qb4, hp, 528); }
      if (!__all(v5)) { LDQ(qa5, hp, 640); LDQ(qb5, hp, 656); }
      asm volatile("s_waitcnt vmcnt(0)" ::: "memory");
      __builtin_amdgcn_sched_barrier(0);
      v0 = tagok(qa0, qb0, tag);
      v1 = tagok(qa1, qb1, tag);
      v2 = tagok(qa2, qb2, tag);
      v3 = tagok(qa3, qb3, tag);
      v4 = tagok(qa4, qb4, tag);
      v5 = tagok(qa5, qb5, tag);
      if (__all(v0 && v1 && v2 && v3 && v4 && v5)) break;
    }
    short8 a0 = rp(qa0, qb0), a1 = rp(qa1, qb1), a2 = rp(qa2, qb2);
    short8 a3 = rp(qa3, qb3), a4 = rp(qa4, qb4), a5 = rp(qa5, qb5);

    f32x4 acc0 = (f32x4){0,0,0,0}, acc1 = (f32x4){0,0,0,0};
    f32x4 acc2 = (f32x4){0,0,0,0}, acc3 = (f32x4){0,0,0,0};
#define MF4(aa, j) \
    acc0 = __builtin_amdgcn_mfma_f32_16x16x32_bf16(aa, bfr[j][0], acc0, 0, 0, 0); \
    acc1 = __builtin_amdgcn_mfma_f32_16x16x32_bf16(aa, bfr[j][1], acc1, 0, 0, 0); \
    acc2 = __builtin_amdgcn_mfma_f32_16x16x32_bf16(aa, bfr[j][2], acc2, 0, 0, 0); \
    acc3 = __builtin_amdgcn_mfma_f32_16x16x32_bf16(aa, bfr[j][3], acc3, 0, 0, 0);
    MF4(a0, 0) MF4(a1, 1) MF4(a2, 2) MF4(a3, 3) MF4(a4, 4) MF4(a5, 5)
#undef MF4

    // cross-wave K reduce via LDS (double-buffered; one intra-WG sync per step)
    f32x4* R = REDS[t & 1];
    R[wv * 256 + 0 * 64 + lane] = acc0;
    R[wv * 256 + 1 * 64 + lane] = acc1;
    R[wv * 256 + 2 * 64 + lane] = acc2;
    R[wv * 256 + 3 * 64 + lane] = acc3;
    __syncthreads();
    float s0 = 0.f, s1 = 0.f;
#pragma unroll
    for (int w2 = 0; w2 < 8; ++w2) {
      s0 += R[w2 * 256 + f0 * 64 + l2a][ri];
      s1 += R[w2 * 256 + f0 * 64 + l2b][ri];
    }

    // critical path: h_new + tagged coherent store (fire-and-forget)
    float h0v = tanhf(pa + sv * s0);
    float h1v = tanhf(pay + sv * s1);
    if (!last) {
      unsigned tw = (unsigned)((t + 1) & 255);
      unsigned w0 = ((unsigned)(unsigned short)f2bf(h0v) << 16) | tw;
      unsigned w1 = ((unsigned)(unsigned short)f2bf(h1v) << 16) | tw;
      st_coh_b64((u64*)(Hn + eidx), (u64)w0 | ((u64)w1 << 32));
    }

    // tail: hall / outs stores (plain cached)
    size_t tb = (size_t)t * BD;
    hall[tb + BD + eidx] = h0v;
    hall[tb + BD + eidx + 1] = h1v;
    outs[tb + eidx]     = h0v * (pz  / (1.f + __expf(-pz)));
    outs[tb + eidx + 1] = h1v * (pzy / (1.f + __expf(-pzy)));
    pa = pan; pay = payn; pz = pzn; pzy = pzyn;
  }
}

// ---------------- launcher ----------------
extern "C" void kernel_launch(void* const* d_in, const int* in_sizes, int n_in,
                              void* d_out, int out_size, void* d_ws, size_t ws_size,
                              hipStream_t stream) {
  const float* x  = (const float*)d_in[0];
  const float* z  = (const float*)d_in[1];
  const float* h0 = (const float*)d_in[2];
  const float* Wx = (const float*)d_in[3];
  const float* Wh = (const float*)d_in[4];
  const float* b  = (const float*)d_in[5];
  const float* lr = (const float*)d_in[6];
  const float* u  = (const float*)d_in[7];

  float* outs = (float*)d_out;
  float* hall = outs + (size_t)TBD;

  char* ws = (char*)d_ws;
  float* vA = (float*)ws;
  float* vB = vA + DD;
  float* vC = vB + DD;
  float* vD = vC + DD;
  float* sS = vD + DD;
  float* hb0 = (float*)(ws + 32768);      // tagged f32 h buffers (2 x 384 KB)
  float* hb1 = hb0 + BD;

  // phase 1: big GEMM (independent; enqueue first)
  hipLaunchKernelGGL(k_gemm_xA, dim3(12, 256), dim3(256), 0, stream, x, Wx, b, outs);

  // invalidate h buffers: 0xFF -> tag 255, mismatches wanted tags 0/1 at t=0/1
  hipMemsetAsync(hb0, 0xFF, (size_t)2 * BD * sizeof(float), stream);

  // phase 0: power iteration
  hipMemsetAsync(vA, 0, DD * sizeof(float), stream);
  hipLaunchKernelGGL(k_matvec_col, dim3(6, 8), dim3(256), 0, stream, Wh, u, vA);
  hipLaunchKernelGGL(k_matvec_row, dim3(384), dim3(256), 0, stream, Wh, vA, vB);
  hipMemsetAsync(vA, 0, DD * sizeof(float), stream);
  hipLaunchKernelGGL(k_matvec_col, dim3(6, 8), dim3(256), 0, stream, Wh, vB, vA);
  hipLaunchKernelGGL(k_matvec_row, dim3(384), dim3(256), 0, stream, Wh, vA, vB);
  hipMemsetAsync(vC, 0, DD * sizeof(float), stream);
  hipLaunchKernelGGL(k_matvec_col, dim3(6, 8), dim3(256), 0, stream, Wh, vB, vC);
  hipLaunchKernelGGL(k_matvec_row, dim3(384), dim3(256), 0, stream, Wh, vC, vD);
  hipLaunchKernelGGL(k_scale, dim3(1), dim3(256), 0, stream, vC, vD, lr, sS);

  // phase 2: cooperative launch (co-residency guaranteed)
  void* args[8] = {(void*)&Wh, (void*)&h0, (void*)&z, (void*)&sS,
                   (void*)&outs, (void*)&hall, (void*)&hb0, (void*)&hb1};
  hipLaunchCooperativeKernel((const void*)k_recur, dim3(NWG), dim3(512), args, 0, stream);
}

// Round 10
// 3020.517 us; speedup vs baseline: 1.1089x; 1.1089x over previous
//
#include <hip/hip_runtime.h>

#define DD 1536
#define TT 512
#define BB 64
#define BD (BB*DD)      /* 98304 */
#define TBD (TT*BD)     /* 50331648 */
#define NWG 96          /* 24 feature-groups x 4 batch-quadrants */

typedef __attribute__((ext_vector_type(8))) short short8;
typedef __attribute__((ext_vector_type(4))) float f32x4;

__device__ __forceinline__ short f2bf(float f) {
  unsigned u = __builtin_bit_cast(unsigned, f);
  u += 0x7FFFu + ((u >> 16) & 1u);   // RNE
  return (short)(u >> 16);
}

// coherent (device-scope, L1/L2-bypassing) 4B store -> Infinity Cache
__device__ __forceinline__ void st_coh_b32(int* p, int v) {
  asm volatile("global_store_dword %0, %1, off sc0 sc1" :: "v"(p), "v"(v) : "memory");
}

// coherent 16B load from Infinity Cache (bypasses L1/L2)
#define LDQ(dst, addr, imm) \
  asm volatile("global_load_dwordx4 %0, %1, off offset:" #imm " sc0 sc1" \
               : "=v"(dst) : "v"(addr) : "memory")

// ---------------- power iteration helpers (f32 exact) ----------------

__global__ __launch_bounds__(256) void k_matvec_row(
    const float* __restrict__ W, const float* __restrict__ x, float* __restrict__ y) {
  int wave = (blockIdx.x * 256 + threadIdx.x) >> 6;
  int lane = threadIdx.x & 63;
  const float* Wr = W + (size_t)wave * DD;
  float acc = 0.f;
  for (int j = lane; j < DD; j += 64) acc += Wr[j] * x[j];
  for (int off = 32; off; off >>= 1) acc += __shfl_down(acc, off, 64);
  if (lane == 0) y[wave] = acc;
}

// y[j] = sum_i W[i,j] x[i] — atomic-free, 6 WGs, full-i loop, coalesced rows
__global__ __launch_bounds__(256) void k_matvec_colf(
    const float* __restrict__ W, const float* __restrict__ x, float* __restrict__ y) {
  int j = blockIdx.x * 256 + threadIdx.x;
  float a0 = 0.f, a1 = 0.f, a2 = 0.f, a3 = 0.f;
  for (int i = 0; i < DD; i += 4) {
    a0 += W[(size_t)(i + 0) * DD + j] * x[i + 0];
    a1 += W[(size_t)(i + 1) * DD + j] * x[i + 1];
    a2 += W[(size_t)(i + 2) * DD + j] * x[i + 2];
    a3 += W[(size_t)(i + 3) * DD + j] * x[i + 3];
  }
  y[j] = (a0 + a1) + (a2 + a3);
}

__global__ __launch_bounds__(256) void k_scale(
    const float* __restrict__ t5, const float* __restrict__ t6,
    const float* __restrict__ log_radius, float* __restrict__ s_out) {
  __shared__ float red[8];
  int tid = threadIdx.x;
  float a5 = 0.f, a6 = 0.f;
  for (int i = tid; i < DD; i += 256) { float v5 = t5[i], v6 = t6[i]; a5 += v5*v5; a6 += v6*v6; }
  for (int off = 32; off; off >>= 1) { a5 += __shfl_down(a5, off, 64); a6 += __shfl_down(a6, off, 64); }
  int w = tid >> 6, lane = tid & 63;
  if (lane == 0) { red[w] = a5; red[4 + w] = a6; }
  __syncthreads();
  if (tid == 0) {
    float s5 = red[0] + red[1] + red[2] + red[3];
    float s6 = red[4] + red[5] + red[6] + red[7];
    float sigma = sqrtf(s6 / s5);
    float lr = log_radius[0];
    float target = 0.999f / (1.f + expf(-lr));
    s_out[0] = target / (sigma + 1e-8f);
  }
}

// ---------------- phase 1: A = x @ Wx^T + b -> d_out[outs region] ----------------
__global__ __launch_bounds__(256) void k_gemm_xA(
    const float* __restrict__ x, const float* __restrict__ Wx,
    const float* __restrict__ bias, float* __restrict__ Aout) {
  __shared__ short As[128 * 64];
  __shared__ short Bs[128 * 64];
  const int tid = threadIdx.x;
  const int lane = tid & 63;
  const int w = tid >> 6;
  const int n0 = blockIdx.x * 128;
  const int m0 = blockIdx.y * 128;
  const int mq = (w >> 1) * 64;
  const int nq = (w & 1) * 64;

  f32x4 acc[4][4];
#pragma unroll
  for (int i = 0; i < 4; ++i)
#pragma unroll
    for (int j = 0; j < 4; ++j) acc[i][j] = (f32x4){0.f, 0.f, 0.f, 0.f};

  const int r0 = tid >> 3;
  const int c8 = tid & 7;

  for (int k0 = 0; k0 < DD; k0 += 64) {
    __syncthreads();
#pragma unroll
    for (int c = 0; c < 4; ++c) {
      int row = c * 32 + r0;
      const float4* gx = (const float4*)(x + (size_t)(m0 + row) * DD + k0 + c8 * 8);
      const float4* gw = (const float4*)(Wx + (size_t)(n0 + row) * DD + k0 + c8 * 8);
      float4 x0 = gx[0], x1 = gx[1];
      float4 w0 = gw[0], w1 = gw[1];
      short8 xv, wv;
      xv[0]=f2bf(x0.x); xv[1]=f2bf(x0.y); xv[2]=f2bf(x0.z); xv[3]=f2bf(x0.w);
      xv[4]=f2bf(x1.x); xv[5]=f2bf(x1.y); xv[6]=f2bf(x1.z); xv[7]=f2bf(x1.w);
      wv[0]=f2bf(w0.x); wv[1]=f2bf(w0.y); wv[2]=f2bf(w0.z); wv[3]=f2bf(w0.w);
      wv[4]=f2bf(w1.x); wv[5]=f2bf(w1.y); wv[6]=f2bf(w1.z); wv[7]=f2bf(w1.w);
      int so = (row * 64 + c8 * 8) ^ ((row & 7) << 3);
      *(short8*)&As[so] = xv;
      *(short8*)&Bs[so] = wv;
    }
    __syncthreads();
#pragma unroll
    for (int kk = 0; kk < 64; kk += 32) {
      short8 af[4], bfr[4];
#pragma unroll
      for (int f = 0; f < 4; ++f) {
        int ar = mq + f * 16 + (lane & 15);
        int k = kk + ((lane >> 4) << 3);
        af[f] = *(const short8*)&As[(ar * 64 + k) ^ ((ar & 7) << 3)];
        int br = nq + f * 16 + (lane & 15);
        bfr[f] = *(const short8*)&Bs[(br * 64 + k) ^ ((br & 7) << 3)];
      }
#pragma unroll
      for (int i = 0; i < 4; ++i)
#pragma unroll
        for (int j = 0; j < 4; ++j)
          acc[i][j] = __builtin_amdgcn_mfma_f32_16x16x32_bf16(af[i], bfr[j], acc[i][j], 0, 0, 0);
    }
  }
#pragma unroll
  for (int i = 0; i < 4; ++i) {
    int rbase = m0 + mq + i * 16 + ((lane >> 4) << 2);
#pragma unroll
    for (int j = 0; j < 4; ++j) {
      int col = n0 + nq + j * 16 + (lane & 15);
      float bv = bias[col];
#pragma unroll
      for (int r = 0; r < 4; ++r)
        Aout[(size_t)(rbase + r) * DD + col] = acc[i][j][r] + bv;
    }
  }
}

// ---------------- phase 2: recurrence, per-wave sub-flags + 3-buffer rotation ----------------
// WG (fg, mq): rows 16*mq..+15, features 64*fg..+63, full K=1536 over 8 waves.
// Sub-flag[(mq*24+fg)*8+wv] = generation, set by wave wv's lane0 right after ITS
// h-store ack (no 2nd syncthreads). Consumer wave waits its 3 producer WGs x 8
// waves = 24 sub-flags (lanes 0..23). 3-buffer rotation closes the 2-buffer
// anti-dependency race: flag>=t+2 transitively implies all 24 same-mq WGs >= t+1,
// i.e. all reads of h[t-1] (the buffer being overwritten) are complete.
__global__ __launch_bounds__(512, 1) void k_recur(
    const float* __restrict__ Wh, const float* __restrict__ h0,
    const float* __restrict__ z, const float* __restrict__ sp,
    float* __restrict__ outs, float* __restrict__ hall,
    short* __restrict__ hbuf, int* __restrict__ flags) {
  __shared__ f32x4 REDS[2][2048];  // double-buffered: 2 x 32 KB
  const int tid = threadIdx.x;
  const int lane = tid & 63;
  const int wv = tid >> 6;         // 0..7
  const int wgid = blockIdx.x;     // 0..95
  const int fg = wgid >> 2;        // 0..23
  const int mq = wgid & 3;
  const int n0 = fg * 64;
  const int m0 = mq * 16;

  const int nl = lane & 15;
  const int hi8 = (lane >> 4) << 3;
  const int kw = wv * 192;         // wave's K-slice base

  // ---- one-time: Wh tile -> registers (f32 -> bf16) ----
  short8 bfr[6][4];
#pragma unroll
  for (int j = 0; j < 6; ++j)
#pragma unroll
    for (int f = 0; f < 4; ++f) {
      const float* gp = Wh + (size_t)(n0 + f * 16 + nl) * DD + kw + j * 32 + hi8;
      float4 a0 = *(const float4*)gp;
      float4 a1 = *(const float4*)(gp + 4);
      short8 v;
      v[0]=f2bf(a0.x); v[1]=f2bf(a0.y); v[2]=f2bf(a0.z); v[3]=f2bf(a0.w);
      v[4]=f2bf(a1.x); v[5]=f2bf(a1.y); v[6]=f2bf(a1.z); v[7]=f2bf(a1.w);
      bfr[j][f] = v;
    }

  // epilogue geometry: 2 consecutive outputs per thread; wave wv owns rows {2wv, 2wv+1}
  const int o = tid * 2;
  const int r = o >> 6;            // 0..15
  const int c = o & 63;            // even
  const int f0 = c >> 4;
  const int c15 = c & 15;
  const int l2a = ((r >> 2) << 4) | c15;
  const int l2b = l2a + 1;
  const int ri = r & 3;
  const size_t eidx = (size_t)(m0 + r) * DD + n0 + c;       // element in [B,D]
  const size_t aoff = (size_t)(m0 + nl) * DD + kw + hi8;    // A-load base, shorts

  int* myflag = flags + ((mq * 24 + fg) * 8 + wv) * 16;     // own 64B line
  const int* cflag = flags + (((mq * 24 + wv * 3 + (lane >> 3)) * 8) + (lane & 7)) * 16;

  // 3 rotating h buffers
  short* pg = hbuf;                // read  h[t]
  short* pn = hbuf + BD;           // write h[t+1]
  short* pq = hbuf + 2 * BD;       // spare

  // init: hall[0] = h0 (f32); buf0 = bf16(h0) coherent packed; per-wave flag gen 1
  {
    float vx = h0[eidx], vy = h0[eidx + 1];
    hall[eidx] = vx; hall[eidx + 1] = vy;
    unsigned pk = (unsigned)(unsigned short)f2bf(vx)
                | ((unsigned)(unsigned short)f2bf(vy) << 16);
    st_coh_b32((int*)(pg + eidx), (int)pk);
  }
  const float sv = sp[0];
  asm volatile("s_waitcnt vmcnt(0)" ::: "memory");
  if (lane == 0) st_coh_b32(myflag, 1);

  // prefetch A, z for t = 0 (plain cached; drains during first spin)
  float pa = outs[eidx], pay = outs[eidx + 1];
  float pz = z[eidx], pzy = z[eidx + 1];

  for (int t = 0; t < TT; ++t) {
    const bool last = (t == TT - 1);

    // wait the 24 producer sub-flags (3 WGs x 8 waves); monotonic, bounded
    if (lane < 24) {
      int it = 0;
      for (;;) {
        int v = __hip_atomic_load(cflag, __ATOMIC_RELAXED, __HIP_MEMORY_SCOPE_AGENT);
        if (v >= t + 1 || ++it > (1 << 20)) break;
        __builtin_amdgcn_s_sleep(1);
      }
    }

    // 6 coherent 16B A-loads (wave's 192-k slice of rows m0..m0+15)
    const short* hp = pg + aoff;
    short8 a0, a1, a2, a3, a4, a5;
    LDQ(a0, hp, 0);
    LDQ(a1, hp, 64);
    LDQ(a2, hp, 128);
    LDQ(a3, hp, 192);
    LDQ(a4, hp, 256);
    LDQ(a5, hp, 320);
    asm volatile("s_waitcnt vmcnt(0)" ::: "memory");
    __builtin_amdgcn_sched_barrier(0);

    f32x4 acc0 = (f32x4){0,0,0,0}, acc1 = (f32x4){0,0,0,0};
    f32x4 acc2 = (f32x4){0,0,0,0}, acc3 = (f32x4){0,0,0,0};
#define MF4(aa, j) \
    acc0 = __builtin_amdgcn_mfma_f32_16x16x32_bf16(aa, bfr[j][0], acc0, 0, 0, 0); \
    acc1 = __builtin_amdgcn_mfma_f32_16x16x32_bf16(aa, bfr[j][1], acc1, 0, 0, 0); \
    acc2 = __builtin_amdgcn_mfma_f32_16x16x32_bf16(aa, bfr[j][2], acc2, 0, 0, 0); \
    acc3 = __builtin_amdgcn_mfma_f32_16x16x32_bf16(aa, bfr[j][3], acc3, 0, 0, 0);
    MF4(a0, 0) MF4(a1, 1) MF4(a2, 2) MF4(a3, 3) MF4(a4, 4) MF4(a5, 5)
#undef MF4

    // cross-wave K reduce (double-buffered LDS; single intra-WG sync per step)
    f32x4* R = REDS[t & 1];
    R[wv * 256 + 0 * 64 + lane] = acc0;
    R[wv * 256 + 1 * 64 + lane] = acc1;
    R[wv * 256 + 2 * 64 + lane] = acc2;
    R[wv * 256 + 3 * 64 + lane] = acc3;
    __syncthreads();
    float s0 = 0.f, s1 = 0.f;
#pragma unroll
    for (int w2 = 0; w2 < 8; ++w2) {
      s0 += R[w2 * 256 + f0 * 64 + l2a][ri];
      s1 += R[w2 * 256 + f0 * 64 + l2b][ri];
    }

    // critical path: h_new -> coherent packed store -> per-wave ack -> sub-flag
    float h0v = tanhf(pa + sv * s0);
    float h1v = tanhf(pay + sv * s1);
    if (!last) {
      unsigned pk = (unsigned)(unsigned short)f2bf(h0v)
                  | ((unsigned)(unsigned short)f2bf(h1v) << 16);
      st_coh_b32((int*)(pn + eidx), (int)pk);
      asm volatile("s_waitcnt vmcnt(0)" ::: "memory");   // this wave's h-store acked at IF
      if (lane == 0) st_coh_b32(myflag, t + 2);          // single-writer release
    }

    // off-critical-path tail (drains during the next spin)
    size_t tb = (size_t)t * BD;
    hall[tb + BD + eidx] = h0v;
    hall[tb + BD + eidx + 1] = h1v;
    outs[tb + eidx]     = h0v * (pz  / (1.f + __expf(-pz)));
    outs[tb + eidx + 1] = h1v * (pzy / (1.f + __expf(-pzy)));
    if (!last) {
      size_t nb = tb + BD + eidx;
      pa = outs[nb]; pay = outs[nb + 1];
      pz = z[nb];    pzy = z[nb + 1];
    }
    // rotate buffers: h[t+1] becomes the read buffer
    short* tmp = pg; pg = pn; pn = pq; pq = tmp;
  }
}

// ---------------- launcher ----------------
extern "C" void kernel_launch(void* const* d_in, const int* in_sizes, int n_in,
                              void* d_out, int out_size, void* d_ws, size_t ws_size,
                              hipStream_t stream) {
  const float* x  = (const float*)d_in[0];
  const float* z  = (const float*)d_in[1];
  const float* h0 = (const float*)d_in[2];
  const float* Wx = (const float*)d_in[3];
  const float* Wh = (const float*)d_in[4];
  const float* b  = (const float*)d_in[5];
  const float* lr = (const float*)d_in[6];
  const float* u  = (const float*)d_in[7];

  float* outs = (float*)d_out;
  float* hall = outs + (size_t)TBD;

  char* ws = (char*)d_ws;
  float* vA = (float*)ws;
  float* vB = vA + DD;
  float* vC = vB + DD;
  float* vD = vC + DD;
  float* sS = vD + DD;                    // @24576
  int*   flags = (int*)(ws + 32768);      // 96 WGs x 8 waves x 64B = 48 KB
  short* hbuf  = (short*)(ws + 131072);   // 3 x BD bf16 = 576 KB

  // phase 1: big GEMM (independent; enqueue first)
  hipLaunchKernelGGL(k_gemm_xA, dim3(12, 256), dim3(256), 0, stream, x, Wx, b, outs);

  // phase 0: power iteration (atomic-free col matvec; no memsets)
  hipLaunchKernelGGL(k_matvec_colf, dim3(6),   dim3(256), 0, stream, Wh, u,  vA);
  hipLaunchKernelGGL(k_matvec_row,  dim3(384), dim3(256), 0, stream, Wh, vA, vB);
  hipLaunchKernelGGL(k_matvec_colf, dim3(6),   dim3(256), 0, stream, Wh, vB, vA);
  hipLaunchKernelGGL(k_matvec_row,  dim3(384), dim3(256), 0, stream, Wh, vA, vB);
  hipLaunchKernelGGL(k_matvec_colf, dim3(6),   dim3(256), 0, stream, Wh, vB, vC);
  hipLaunchKernelGGL(k_matvec_row,  dim3(384), dim3(256), 0, stream, Wh, vC, vD);
  hipLaunchKernelGGL(k_scale, dim3(1), dim3(256), 0, stream, vC, vD, lr, sS);

  // zero sub-flag array each launch (graph-capture-safe)
  hipMemsetAsync(flags, 0, 49152, stream);

  // phase 2: cooperative launch (co-residency guaranteed)
  void* args[8] = {(void*)&Wh, (void*)&h0, (void*)&z, (void*)&sS,
                   (void*)&outs, (void*)&hall, (void*)&hbuf, (void*)&flags};
  hipLaunchCooperativeKernel((const void*)k_recur, dim3(NWG), dim3(512), args, 0, stream);
}

// Round 11
// 2465.569 us; speedup vs baseline: 1.3585x; 1.2251x over previous
//
#include <hip/hip_runtime.h>

#define DD 1536
#define TT 512
#define BB 64
#define BD (BB*DD)      /* 98304 */
#define TBD (TT*BD)     /* 50331648 */
#define NWG 96          /* 24 feature-groups x 4 batch-quadrants */

typedef __attribute__((ext_vector_type(8))) short short8;
typedef __attribute__((ext_vector_type(4))) float f32x4;

__device__ __forceinline__ short f2bf(float f) {
  unsigned u = __builtin_bit_cast(unsigned, f);
  u += 0x7FFFu + ((u >> 16) & 1u);   // RNE
  return (short)(u >> 16);
}

// coherent (device-scope, L1/L2-bypassing) 4B store -> Infinity Cache
__device__ __forceinline__ void st_coh_b32(int* p, int v) {
  asm volatile("global_store_dword %0, %1, off sc0 sc1" :: "v"(p), "v"(v) : "memory");
}

// coherent 16B load from Infinity Cache (bypasses L1/L2)
#define LDQ(dst, addr, imm) \
  asm volatile("global_load_dwordx4 %0, %1, off offset:" #imm " sc0 sc1" \
               : "=v"(dst) : "v"(addr) : "memory")

// ---------------- power iteration helpers (f32 exact) ----------------

__global__ __launch_bounds__(256) void k_matvec_row(
    const float* __restrict__ W, const float* __restrict__ x, float* __restrict__ y) {
  int wave = (blockIdx.x * 256 + threadIdx.x) >> 6;
  int lane = threadIdx.x & 63;
  const float* Wr = W + (size_t)wave * DD;
  float acc = 0.f;
  for (int j = lane; j < DD; j += 64) acc += Wr[j] * x[j];
  for (int off = 32; off; off >>= 1) acc += __shfl_down(acc, off, 64);
  if (lane == 0) y[wave] = acc;
}

// y[j] = sum_i W[i,j] x[i] — atomic-free, 6 WGs, full-i loop, coalesced rows
__global__ __launch_bounds__(256) void k_matvec_colf(
    const float* __restrict__ W, const float* __restrict__ x, float* __restrict__ y) {
  int j = blockIdx.x * 256 + threadIdx.x;
  float a0 = 0.f, a1 = 0.f, a2 = 0.f, a3 = 0.f;
  for (int i = 0; i < DD; i += 4) {
    a0 += W[(size_t)(i + 0) * DD + j] * x[i + 0];
    a1 += W[(size_t)(i + 1) * DD + j] * x[i + 1];
    a2 += W[(size_t)(i + 2) * DD + j] * x[i + 2];
    a3 += W[(size_t)(i + 3) * DD + j] * x[i + 3];
  }
  y[j] = (a0 + a1) + (a2 + a3);
}

__global__ __launch_bounds__(256) void k_scale(
    const float* __restrict__ t5, const float* __restrict__ t6,
    const float* __restrict__ log_radius, float* __restrict__ s_out) {
  __shared__ float red[8];
  int tid = threadIdx.x;
  float a5 = 0.f, a6 = 0.f;
  for (int i = tid; i < DD; i += 256) { float v5 = t5[i], v6 = t6[i]; a5 += v5*v5; a6 += v6*v6; }
  for (int off = 32; off; off >>= 1) { a5 += __shfl_down(a5, off, 64); a6 += __shfl_down(a6, off, 64); }
  int w = tid >> 6, lane = tid & 63;
  if (lane == 0) { red[w] = a5; red[4 + w] = a6; }
  __syncthreads();
  if (tid == 0) {
    float s5 = red[0] + red[1] + red[2] + red[3];
    float s6 = red[4] + red[5] + red[6] + red[7];
    float sigma = sqrtf(s6 / s5);
    float lr = log_radius[0];
    float target = 0.999f / (1.f + expf(-lr));
    s_out[0] = target / (sigma + 1e-8f);
  }
}

// ---------------- bf16 pre-conversion (gated on ws_size) ----------------
__global__ __launch_bounds__(256) void k_conv(
    const float* __restrict__ in, short* __restrict__ out, int n8) {
  int i = blockIdx.x * 256 + threadIdx.x;
  int stride = gridDim.x * 256;
  for (; i < n8; i += stride) {
    const float4* p = (const float4*)(in + (size_t)i * 8);
    float4 a = p[0], b = p[1];
    short8 v;
    v[0]=f2bf(a.x); v[1]=f2bf(a.y); v[2]=f2bf(a.z); v[3]=f2bf(a.w);
    v[4]=f2bf(b.x); v[5]=f2bf(b.y); v[6]=f2bf(b.z); v[7]=f2bf(b.w);
    *(short8*)(out + (size_t)i * 8) = v;
  }
}

// ---------------- phase 1a: A = x @ Wx^T + b (f32 inputs, fallback) ----------------
__global__ __launch_bounds__(256) void k_gemm_xA(
    const float* __restrict__ x, const float* __restrict__ Wx,
    const float* __restrict__ bias, float* __restrict__ Aout) {
  __shared__ short As[128 * 64];
  __shared__ short Bs[128 * 64];
  const int tid = threadIdx.x;
  const int lane = tid & 63;
  const int w = tid >> 6;
  const int n0 = blockIdx.x * 128;
  const int m0 = blockIdx.y * 128;
  const int mq = (w >> 1) * 64;
  const int nq = (w & 1) * 64;

  f32x4 acc[4][4];
#pragma unroll
  for (int i = 0; i < 4; ++i)
#pragma unroll
    for (int j = 0; j < 4; ++j) acc[i][j] = (f32x4){0.f, 0.f, 0.f, 0.f};

  const int r0 = tid >> 3;
  const int c8 = tid & 7;

  for (int k0 = 0; k0 < DD; k0 += 64) {
    __syncthreads();
#pragma unroll
    for (int c = 0; c < 4; ++c) {
      int row = c * 32 + r0;
      const float4* gx = (const float4*)(x + (size_t)(m0 + row) * DD + k0 + c8 * 8);
      const float4* gw = (const float4*)(Wx + (size_t)(n0 + row) * DD + k0 + c8 * 8);
      float4 x0 = gx[0], x1 = gx[1];
      float4 w0 = gw[0], w1 = gw[1];
      short8 xv, wv;
      xv[0]=f2bf(x0.x); xv[1]=f2bf(x0.y); xv[2]=f2bf(x0.z); xv[3]=f2bf(x0.w);
      xv[4]=f2bf(x1.x); xv[5]=f2bf(x1.y); xv[6]=f2bf(x1.z); xv[7]=f2bf(x1.w);
      wv[0]=f2bf(w0.x); wv[1]=f2bf(w0.y); wv[2]=f2bf(w0.z); wv[3]=f2bf(w0.w);
      wv[4]=f2bf(w1.x); wv[5]=f2bf(w1.y); wv[6]=f2bf(w1.z); wv[7]=f2bf(w1.w);
      int so = (row * 64 + c8 * 8) ^ ((row & 7) << 3);
      *(short8*)&As[so] = xv;
      *(short8*)&Bs[so] = wv;
    }
    __syncthreads();
#pragma unroll
    for (int kk = 0; kk < 64; kk += 32) {
      short8 af[4], bfr[4];
#pragma unroll
      for (int f = 0; f < 4; ++f) {
        int ar = mq + f * 16 + (lane & 15);
        int k = kk + ((lane >> 4) << 3);
        af[f] = *(const short8*)&As[(ar * 64 + k) ^ ((ar & 7) << 3)];
        int br = nq + f * 16 + (lane & 15);
        bfr[f] = *(const short8*)&Bs[(br * 64 + k) ^ ((br & 7) << 3)];
      }
#pragma unroll
      for (int i = 0; i < 4; ++i)
#pragma unroll
        for (int j = 0; j < 4; ++j)
          acc[i][j] = __builtin_amdgcn_mfma_f32_16x16x32_bf16(af[i], bfr[j], acc[i][j], 0, 0, 0);
    }
  }
#pragma unroll
  for (int i = 0; i < 4; ++i) {
    int rbase = m0 + mq + i * 16 + ((lane >> 4) << 2);
#pragma unroll
    for (int j = 0; j < 4; ++j) {
      int col = n0 + nq + j * 16 + (lane & 15);
      float bv = bias[col];
#pragma unroll
      for (int r = 0; r < 4; ++r)
        Aout[(size_t)(rbase + r) * DD + col] = acc[i][j][r] + bv;
    }
  }
}

// ---------------- phase 1b: same GEMM, bf16 pre-converted inputs ----------------
__global__ __launch_bounds__(256) void k_gemm_b(
    const short* __restrict__ xb, const short* __restrict__ Wxb,
    const float* __restrict__ bias, float* __restrict__ Aout) {
  __shared__ short As[128 * 64];
  __shared__ short Bs[128 * 64];
  const int tid = threadIdx.x;
  const int lane = tid & 63;
  const int w = tid >> 6;
  const int n0 = blockIdx.x * 128;
  const int m0 = blockIdx.y * 128;
  const int mq = (w >> 1) * 64;
  const int nq = (w & 1) * 64;

  f32x4 acc[4][4];
#pragma unroll
  for (int i = 0; i < 4; ++i)
#pragma unroll
    for (int j = 0; j < 4; ++j) acc[i][j] = (f32x4){0.f, 0.f, 0.f, 0.f};

  const int r0 = tid >> 3;
  const int c8 = tid & 7;

  for (int k0 = 0; k0 < DD; k0 += 64) {
    __syncthreads();
#pragma unroll
    for (int c = 0; c < 4; ++c) {
      int row = c * 32 + r0;
      short8 xv = *(const short8*)(xb  + (size_t)(m0 + row) * DD + k0 + c8 * 8);
      short8 wv = *(const short8*)(Wxb + (size_t)(n0 + row) * DD + k0 + c8 * 8);
      int so = (row * 64 + c8 * 8) ^ ((row & 7) << 3);
      *(short8*)&As[so] = xv;
      *(short8*)&Bs[so] = wv;
    }
    __syncthreads();
#pragma unroll
    for (int kk = 0; kk < 64; kk += 32) {
      short8 af[4], bfr[4];
#pragma unroll
      for (int f = 0; f < 4; ++f) {
        int ar = mq + f * 16 + (lane & 15);
        int k = kk + ((lane >> 4) << 3);
        af[f] = *(const short8*)&As[(ar * 64 + k) ^ ((ar & 7) << 3)];
        int br = nq + f * 16 + (lane & 15);
        bfr[f] = *(const short8*)&Bs[(br * 64 + k) ^ ((br & 7) << 3)];
      }
#pragma unroll
      for (int i = 0; i < 4; ++i)
#pragma unroll
        for (int j = 0; j < 4; ++j)
          acc[i][j] = __builtin_amdgcn_mfma_f32_16x16x32_bf16(af[i], bfr[j], acc[i][j], 0, 0, 0);
    }
  }
#pragma unroll
  for (int i = 0; i < 4; ++i) {
    int rbase = m0 + mq + i * 16 + ((lane >> 4) << 2);
#pragma unroll
    for (int j = 0; j < 4; ++j) {
      int col = n0 + nq + j * 16 + (lane & 15);
      float bv = bias[col];
#pragma unroll
      for (int r = 0; r < 4; ++r)
        Aout[(size_t)(rbase + r) * DD + col] = acc[i][j][r] + bv;
    }
  }
}

// ---------------- phase 2: recurrence (R10 protocol + swizzled b32 reduce) ----------------
// Reduce storage: physical quad = w2*256 + f*64 + (l ^ bit5(l)); component slot
// (ri+f)&3 (compile-time rotation at write). Both read instructions hit banks in
// disjoint (f0 + 4*half) classes -> max 2 lanes/bank (free), 4x less LDS traffic.
__global__ __launch_bounds__(512, 1) void k_recur(
    const float* __restrict__ Wh, const float* __restrict__ h0,
    const float* __restrict__ z, const float* __restrict__ sp,
    float* __restrict__ outs, float* __restrict__ hall,
    short* __restrict__ hbuf, int* __restrict__ flags) {
  __shared__ f32x4 REDS[2][2048];  // 2 x 32 KB
  const int tid = threadIdx.x;
  const int lane = tid & 63;
  const int wv = tid >> 6;         // 0..7
  const int wgid = blockIdx.x;     // 0..95
  const int fg = wgid >> 2;        // 0..23
  const int mq = wgid & 3;
  const int n0 = fg * 64;
  const int m0 = mq * 16;

  const int nl = lane & 15;
  const int hi8 = (lane >> 4) << 3;
  const int kw = wv * 192;         // wave's K-slice base

  // ---- one-time: Wh tile -> registers (f32 -> bf16) ----
  short8 bfr[6][4];
#pragma unroll
  for (int j = 0; j < 6; ++j)
#pragma unroll
    for (int f = 0; f < 4; ++f) {
      const float* gp = Wh + (size_t)(n0 + f * 16 + nl) * DD + kw + j * 32 + hi8;
      float4 a0 = *(const float4*)gp;
      float4 a1 = *(const float4*)(gp + 4);
      short8 v;
      v[0]=f2bf(a0.x); v[1]=f2bf(a0.y); v[2]=f2bf(a0.z); v[3]=f2bf(a0.w);
      v[4]=f2bf(a1.x); v[5]=f2bf(a1.y); v[6]=f2bf(a1.z); v[7]=f2bf(a1.w);
      bfr[j][f] = v;
    }

  // epilogue geometry: r = wv + 8*half keeps ri wave-uniform; c,c+1 per thread
  const int r = wv + ((lane >> 5) << 3);   // 0..15
  const int c = (lane & 31) * 2;           // 0..62 even
  const int f0 = c >> 4;
  const int c15 = c & 15;
  const int l2a = ((r >> 2) << 4) | c15;
  const int l2b = l2a + 1;
  const int ri = r & 3;
  const size_t eidx = (size_t)(m0 + r) * DD + n0 + c;       // element in [B,D]
  const size_t aoff = (size_t)(m0 + nl) * DD + kw + hi8;    // A-load base, shorts

  int* myflag = flags + ((mq * 24 + fg) * 8 + wv) * 16;     // own 64B line
  const int* cflag = flags + (((mq * 24 + wv * 3 + (lane >> 3)) * 8) + (lane & 7)) * 16;

  // 3 rotating h buffers
  short* pg = hbuf;                // read  h[t]
  short* pn = hbuf + BD;           // write h[t+1]
  short* pq = hbuf + 2 * BD;       // spare

  // init: hall[0] = h0 (f32); buf0 = bf16(h0) coherent packed; per-wave flag gen 1
  {
    float vx = h0[eidx], vy = h0[eidx + 1];
    hall[eidx] = vx; hall[eidx + 1] = vy;
    unsigned pk = (unsigned)(unsigned short)f2bf(vx)
                | ((unsigned)(unsigned short)f2bf(vy) << 16);
    st_coh_b32((int*)(pg + eidx), (int)pk);
  }
  const float sv = sp[0];
  asm volatile("s_waitcnt vmcnt(0)" ::: "memory");
  if (lane == 0) st_coh_b32(myflag, 1);

  // prefetch A, z for t = 0 (plain cached; drains during first spin)
  float pa = outs[eidx], pay = outs[eidx + 1];
  float pz = z[eidx], pzy = z[eidx + 1];

  for (int t = 0; t < TT; ++t) {
    const bool last = (t == TT - 1);

    // wait the 24 producer sub-flags (3 WGs x 8 waves); monotonic, bounded
    if (lane < 24) {
      int it = 0;
      for (;;) {
        int v = __hip_atomic_load(cflag, __ATOMIC_RELAXED, __HIP_MEMORY_SCOPE_AGENT);
        if (v >= t + 1 || ++it > (1 << 20)) break;
        __builtin_amdgcn_s_sleep(1);
      }
    }

    // 6 coherent 16B A-loads (wave's 192-k slice of rows m0..m0+15)
    const short* hp = pg + aoff;
    short8 a0, a1, a2, a3, a4, a5;
    LDQ(a0, hp, 0);
    LDQ(a1, hp, 64);
    LDQ(a2, hp, 128);
    LDQ(a3, hp, 192);
    LDQ(a4, hp, 256);
    LDQ(a5, hp, 320);
    asm volatile("s_waitcnt vmcnt(0)" ::: "memory");
    __builtin_amdgcn_sched_barrier(0);

    f32x4 acc0 = (f32x4){0,0,0,0}, acc1 = (f32x4){0,0,0,0};
    f32x4 acc2 = (f32x4){0,0,0,0}, acc3 = (f32x4){0,0,0,0};
#define MF4(aa, j) \
    acc0 = __builtin_amdgcn_mfma_f32_16x16x32_bf16(aa, bfr[j][0], acc0, 0, 0, 0); \
    acc1 = __builtin_amdgcn_mfma_f32_16x16x32_bf16(aa, bfr[j][1], acc1, 0, 0, 0); \
    acc2 = __builtin_amdgcn_mfma_f32_16x16x32_bf16(aa, bfr[j][2], acc2, 0, 0, 0); \
    acc3 = __builtin_amdgcn_mfma_f32_16x16x32_bf16(aa, bfr[j][3], acc3, 0, 0, 0);
    MF4(a0, 0) MF4(a1, 1) MF4(a2, 2) MF4(a3, 3) MF4(a4, 4) MF4(a5, 5)
#undef MF4

    // cross-wave K reduce: swizzled writes (component-rotated, bit5-XOR lane)
    f32x4* R = REDS[t & 1];
    {
      const int lsw = lane ^ ((lane >> 5) & 1);
#define WR(f, accv) { f32x4 wv_; \
      wv_[(0 + f) & 3] = accv[0]; wv_[(1 + f) & 3] = accv[1]; \
      wv_[(2 + f) & 3] = accv[2]; wv_[(3 + f) & 3] = accv[3]; \
      R[wv * 256 + f * 64 + lsw] = wv_; }
      WR(0, acc0) WR(1, acc1) WR(2, acc2) WR(3, acc3)
#undef WR
    }
    __syncthreads();
    const float* Rf = (const float*)R;
    const int ia = (f0 * 64 + (l2a ^ ((l2a >> 5) & 1))) * 4 + ((ri + f0) & 3);
    const int ib = (f0 * 64 + (l2b ^ ((l2b >> 5) & 1))) * 4 + ((ri + f0) & 3);
    float s0 = 0.f, s1 = 0.f;
#pragma unroll
    for (int w2 = 0; w2 < 8; ++w2) {
      s0 += Rf[w2 * 1024 + ia];
      s1 += Rf[w2 * 1024 + ib];
    }

    // critical path: h_new -> coherent packed store -> per-wave ack -> sub-flag
    float h0v = tanhf(pa + sv * s0);
    float h1v = tanhf(pay + sv * s1);
    if (!last) {
      unsigned pk = (unsigned)(unsigned short)f2bf(h0v)
                  | ((unsigned)(unsigned short)f2bf(h1v) << 16);
      st_coh_b32((int*)(pn + eidx), (int)pk);
      asm volatile("s_waitcnt vmcnt(0)" ::: "memory");   // this wave's h-store acked at IF
      if (lane == 0) st_coh_b32(myflag, t + 2);          // single-writer release
    }

    // off-critical-path tail (drains during the next spin)
    size_t tb = (size_t)t * BD;
    hall[tb + BD + eidx] = h0v;
    hall[tb + BD + eidx + 1] = h1v;
    outs[tb + eidx]     = h0v * (pz  / (1.f + __expf(-pz)));
    outs[tb + eidx + 1] = h1v * (pzy / (1.f + __expf(-pzy)));
    if (!last) {
      size_t nb = tb + BD + eidx;
      pa = outs[nb]; pay = outs[nb + 1];
      pz = z[nb];    pzy = z[nb + 1];
    }
    // rotate buffers: h[t+1] becomes the read buffer
    short* tmp = pg; pg = pn; pn = pq; pq = tmp;
  }
}

// ---------------- launcher ----------------
extern "C" void kernel_launch(void* const* d_in, const int* in_sizes, int n_in,
                              void* d_out, int out_size, void* d_ws, size_t ws_size,
                              hipStream_t stream) {
  const float* x  = (const float*)d_in[0];
  const float* z  = (const float*)d_in[1];
  const float* h0 = (const float*)d_in[2];
  const float* Wx = (const float*)d_in[3];
  const float* Wh = (const float*)d_in[4];
  const float* b  = (const float*)d_in[5];
  const float* lr = (const float*)d_in[6];
  const float* u  = (const float*)d_in[7];

  float* outs = (float*)d_out;
  float* hall = outs + (size_t)TBD;

  char* ws = (char*)d_ws;
  float* vA = (float*)ws;
  float* vB = vA + DD;
  float* vC = vB + DD;
  float* vD = vC + DD;
  float* sS = vD + DD;                    // @24576
  int*   flags = (int*)(ws + 32768);      // 96 WGs x 8 waves x 64B = 48 KB
  short* hbuf  = (short*)(ws + 131072);   // 3 x BD bf16 = 576 KB

  // bf16 scratch (gated): x bf16 (~96 MB) + Wx bf16 (~4.5 MB) at 16 MB offset
  short* xb  = (short*)(ws + ((size_t)16 << 20));
  short* Wxb = xb + (size_t)TBD;
  const size_t need = ((size_t)16 << 20) + ((size_t)TBD + (size_t)DD * DD) * 2 + 1024;
  const bool big = ws_size >= need;

  // phase 1: big GEMM (independent; enqueue first)
  if (big) {
    hipLaunchKernelGGL(k_conv, dim3(2048), dim3(256), 0, stream, x,  xb,  TBD / 8);
    hipLaunchKernelGGL(k_conv, dim3(512),  dim3(256), 0, stream, Wx, Wxb, DD * DD / 8);
    hipLaunchKernelGGL(k_gemm_b, dim3(12, 256), dim3(256), 0, stream, xb, Wxb, b, outs);
  } else {
    hipLaunchKernelGGL(k_gemm_xA, dim3(12, 256), dim3(256), 0, stream, x, Wx, b, outs);
  }

  // phase 0: power iteration (atomic-free col matvec)
  hipLaunchKernelGGL(k_matvec_colf, dim3(6),   dim3(256), 0, stream, Wh, u,  vA);
  hipLaunchKernelGGL(k_matvec_row,  dim3(384), dim3(256), 0, stream, Wh, vA, vB);
  hipLaunchKernelGGL(k_matvec_colf, dim3(6),   dim3(256), 0, stream, Wh, vB, vA);
  hipLaunchKernelGGL(k_matvec_row,  dim3(384), dim3(256), 0, stream, Wh, vA, vB);
  hipLaunchKernelGGL(k_matvec_colf, dim3(6),   dim3(256), 0, stream, Wh, vB, vC);
  hipLaunchKernelGGL(k_matvec_row,  dim3(384), dim3(256), 0, stream, Wh, vC, vD);
  hipLaunchKernelGGL(k_scale, dim3(1), dim3(256), 0, stream, vC, vD, lr, sS);

  // zero sub-flag array each launch (graph-capture-safe)
  hipMemsetAsync(flags, 0, 49152, stream);

  // phase 2: cooperative launch (co-residency guaranteed)
  void* args[8] = {(void*)&Wh, (void*)&h0, (void*)&z, (void*)&sS,
                   (void*)&outs, (void*)&hall, (void*)&hbuf, (void*)&flags};
  hipLaunchCooperativeKernel((const void*)k_recur, dim3(NWG), dim3(512), args, 0, stream);
}